// Round 1
// baseline (737.815 us; speedup 1.0000x reference)
//
#include <hip/hip_runtime.h>
#include <math.h>

#define NBATCH 32
#define NCH    512
#define NHW    1024
#define NL     77
#define ND     768
#define NHEADS 8

// ============================================================
// Kernel 1: GroupNorm statistics. One block per (b, g); group is
// 16 channels x 1024 = 16384 contiguous floats.
// ============================================================
__global__ __launch_bounds__(256) void k_gn_stats(const float* __restrict__ x,
                                                  float* __restrict__ mu_out,
                                                  float* __restrict__ rs_out) {
    const int bg = blockIdx.x;  // b*32 + g
    const float4* xv = reinterpret_cast<const float4*>(x) + (size_t)bg * 4096;
    float s = 0.f, q = 0.f;
#pragma unroll
    for (int i = 0; i < 16; ++i) {
        float4 v = xv[i * 256 + threadIdx.x];
        s += v.x + v.y + v.z + v.w;
        q += v.x * v.x + v.y * v.y + v.z * v.z + v.w * v.w;
    }
#pragma unroll
    for (int off = 32; off > 0; off >>= 1) {
        s += __shfl_down(s, off);
        q += __shfl_down(q, off);
    }
    __shared__ float rsh[8];
    const int wid = threadIdx.x >> 6;
    if ((threadIdx.x & 63) == 0) { rsh[wid] = s; rsh[4 + wid] = q; }
    __syncthreads();
    if (threadIdx.x == 0) {
        const float S  = rsh[0] + rsh[1] + rsh[2] + rsh[3];
        const float Q  = rsh[4] + rsh[5] + rsh[6] + rsh[7];
        const float mu = S * (1.f / 16384.f);
        const float var = Q * (1.f / 16384.f) - mu * mu;
        mu_out[bg] = mu;
        rs_out[bg] = 1.f / sqrtf(var + 1e-5f);
    }
}

// ============================================================
// Kernel 2: LayerNorm of t. One wave per row (768 elements).
// 616 blocks x 256 threads = 2464 rows.
// ============================================================
__global__ __launch_bounds__(256) void k_ln(const float* __restrict__ t,
                                            const float* __restrict__ lw,
                                            const float* __restrict__ lb,
                                            float* __restrict__ tln) {
    const int row  = blockIdx.x * 4 + (threadIdx.x >> 6);
    const int lane = threadIdx.x & 63;
    const float4* tv = reinterpret_cast<const float4*>(t + (size_t)row * ND);
    float4 v[3];
    float s = 0.f, q = 0.f;
#pragma unroll
    for (int j = 0; j < 3; ++j) {
        v[j] = tv[lane + j * 64];
        s += v[j].x + v[j].y + v[j].z + v[j].w;
        q += v[j].x * v[j].x + v[j].y * v[j].y + v[j].z * v[j].z + v[j].w * v[j].w;
    }
#pragma unroll
    for (int off = 32; off > 0; off >>= 1) {
        s += __shfl_down(s, off);
        q += __shfl_down(q, off);
    }
    s = __shfl(s, 0);
    q = __shfl(q, 0);
    const float mu  = s * (1.f / 768.f);
    const float rsg = 1.f / sqrtf(q * (1.f / 768.f) - mu * mu + 1e-5f);
    float4* ov = reinterpret_cast<float4*>(tln + (size_t)row * ND);
    const float4* wv = reinterpret_cast<const float4*>(lw);
    const float4* bv = reinterpret_cast<const float4*>(lb);
#pragma unroll
    for (int j = 0; j < 3; ++j) {
        const float4 w = wv[lane + j * 64];
        const float4 bb = bv[lane + j * 64];
        float4 o;
        o.x = (v[j].x - mu) * rsg * w.x + bb.x;
        o.y = (v[j].y - mu) * rsg * w.y + bb.y;
        o.z = (v[j].z - mu) * rsg * w.z + bb.z;
        o.w = (v[j].w - mu) * rsg * w.w + bb.w;
        ov[lane + j * 64] = o;
    }
}

// ============================================================
// Kernel 3: KV projection GEMM.
// kv[m][n] = sum_k tln[m][k] * Wkv[n][k];  M=2464, N=1024, K=768.
// 64x128 tile, 256 threads, 4x8 per thread, BK=16.
// ============================================================
__global__ __launch_bounds__(256) void k_kv(const float* __restrict__ A,
                                            const float* __restrict__ Wkv,
                                            float* __restrict__ kvout) {
    __shared__ float As[16][68];
    __shared__ float Bs[16][132];
    const int n0 = blockIdx.x * 128;
    const int m0 = blockIdx.y * 64;
    const int tid = threadIdx.x;
    const int tm = tid & 15, tn = tid >> 4;
    float acc[4][8];
#pragma unroll
    for (int i = 0; i < 4; ++i)
#pragma unroll
        for (int j = 0; j < 8; ++j) acc[i][j] = 0.f;

    const int arow = tid >> 2, ak4 = (tid & 3) * 4;   // A: 64 rows x 16 k
    const int brow = tid >> 1, bk8 = (tid & 1) * 8;   // B: 128 rows x 16 k
    const int arow_g = min(m0 + arow, 2463);          // clamp tail rows (stores guarded)
    const float* Aptr = A + (size_t)arow_g * ND;
    const float* Bptr = Wkv + (size_t)(n0 + brow) * ND;

    for (int k0 = 0; k0 < ND; k0 += 16) {
        const float4 av = *reinterpret_cast<const float4*>(Aptr + k0 + ak4);
        const float4 b0 = *reinterpret_cast<const float4*>(Bptr + k0 + bk8);
        const float4 b1 = *reinterpret_cast<const float4*>(Bptr + k0 + bk8 + 4);
        As[ak4 + 0][arow] = av.x; As[ak4 + 1][arow] = av.y;
        As[ak4 + 2][arow] = av.z; As[ak4 + 3][arow] = av.w;
        Bs[bk8 + 0][brow] = b0.x; Bs[bk8 + 1][brow] = b0.y;
        Bs[bk8 + 2][brow] = b0.z; Bs[bk8 + 3][brow] = b0.w;
        Bs[bk8 + 4][brow] = b1.x; Bs[bk8 + 5][brow] = b1.y;
        Bs[bk8 + 6][brow] = b1.z; Bs[bk8 + 7][brow] = b1.w;
        __syncthreads();
#pragma unroll
        for (int k = 0; k < 16; ++k) {
            const float4 a  = *reinterpret_cast<const float4*>(&As[k][tm * 4]);
            const float4 p0 = *reinterpret_cast<const float4*>(&Bs[k][tn * 8]);
            const float4 p1 = *reinterpret_cast<const float4*>(&Bs[k][tn * 8 + 4]);
            const float aa[4] = {a.x, a.y, a.z, a.w};
            const float bb[8] = {p0.x, p0.y, p0.z, p0.w, p1.x, p1.y, p1.z, p1.w};
#pragma unroll
            for (int i = 0; i < 4; ++i)
#pragma unroll
                for (int j = 0; j < 8; ++j)
                    acc[i][j] = fmaf(aa[i], bb[j], acc[i][j]);
        }
        __syncthreads();
    }
#pragma unroll
    for (int i = 0; i < 4; ++i) {
        const int m = m0 + tm * 4 + i;
        if (m < 2464) {
            float* orow = kvout + (size_t)m * 1024 + n0 + tn * 8;
            *reinterpret_cast<float4*>(orow)     = make_float4(acc[i][0], acc[i][1], acc[i][2], acc[i][3]);
            *reinterpret_cast<float4*>(orow + 4) = make_float4(acc[i][4], acc[i][5], acc[i][6], acc[i][7]);
        }
    }
}

// ============================================================
// Kernels 4/6: projection GEMM per batch.
// out[b][o][n] = sum_c W[o][c] * Xb[c][n] (+ epilogue)
// MODE 0 (q-proj): Xb = GN-normalized x (applied on load), plain store.
// MODE 1 (out-proj): Xb = h buffer; epilogue adds bp[o] + x residual.
// 128x128 tile, 256 threads, 8x8 per thread, BK=16. M=512,N=1024,K=512.
// ============================================================
template <int MODE>
__global__ __launch_bounds__(256) void k_proj(const float* __restrict__ W,
                                              const float* __restrict__ Xsrc,
                                              const float* __restrict__ mu,
                                              const float* __restrict__ rsg,
                                              const float* __restrict__ gw,
                                              const float* __restrict__ gb,
                                              const float* __restrict__ bp,
                                              const float* __restrict__ xres,
                                              float* __restrict__ outp) {
    __shared__ float As[16][132];
    __shared__ float Bs[16][132];
    const int b  = blockIdx.z;
    const int n0 = blockIdx.x * 128;
    const int m0 = blockIdx.y * 128;
    const int tid = threadIdx.x;
    const int tm = tid & 15, tn = tid >> 4;
    const float* Xb = Xsrc + (size_t)b * NCH * NHW;
    float acc[8][8];
#pragma unroll
    for (int i = 0; i < 8; ++i)
#pragma unroll
        for (int j = 0; j < 8; ++j) acc[i][j] = 0.f;

    const int arow = tid >> 1, ak8 = (tid & 1) * 8;   // A: 128 rows x 16 k
    const int bc = tid >> 5, bn4 = (tid & 31) * 4;    // B: rows bc, bc+8 x 128 n
    const float* Wr = W + (size_t)(m0 + arow) * NCH;

    for (int k0 = 0; k0 < NCH; k0 += 16) {
        const float4 a0 = *reinterpret_cast<const float4*>(Wr + k0 + ak8);
        const float4 a1 = *reinterpret_cast<const float4*>(Wr + k0 + ak8 + 4);
        const int c1 = k0 + bc, c2 = c1 + 8;
        float4 v1 = *reinterpret_cast<const float4*>(Xb + (size_t)c1 * NHW + n0 + bn4);
        float4 v2 = *reinterpret_cast<const float4*>(Xb + (size_t)c2 * NHW + n0 + bn4);
        if constexpr (MODE == 0) {
            const float r1 = rsg[b * 32 + (c1 >> 4)], m1 = mu[b * 32 + (c1 >> 4)];
            const float sc1 = r1 * gw[c1];
            const float sh1 = gb[c1] - m1 * sc1;
            v1.x = v1.x * sc1 + sh1; v1.y = v1.y * sc1 + sh1;
            v1.z = v1.z * sc1 + sh1; v1.w = v1.w * sc1 + sh1;
            const float r2 = rsg[b * 32 + (c2 >> 4)], m2 = mu[b * 32 + (c2 >> 4)];
            const float sc2 = r2 * gw[c2];
            const float sh2 = gb[c2] - m2 * sc2;
            v2.x = v2.x * sc2 + sh2; v2.y = v2.y * sc2 + sh2;
            v2.z = v2.z * sc2 + sh2; v2.w = v2.w * sc2 + sh2;
        }
        As[ak8 + 0][arow] = a0.x; As[ak8 + 1][arow] = a0.y;
        As[ak8 + 2][arow] = a0.z; As[ak8 + 3][arow] = a0.w;
        As[ak8 + 4][arow] = a1.x; As[ak8 + 5][arow] = a1.y;
        As[ak8 + 6][arow] = a1.z; As[ak8 + 7][arow] = a1.w;
        *reinterpret_cast<float4*>(&Bs[bc][bn4])     = v1;
        *reinterpret_cast<float4*>(&Bs[bc + 8][bn4]) = v2;
        __syncthreads();
#pragma unroll
        for (int k = 0; k < 16; ++k) {
            const float4 a0v = *reinterpret_cast<const float4*>(&As[k][tm * 8]);
            const float4 a1v = *reinterpret_cast<const float4*>(&As[k][tm * 8 + 4]);
            const float4 b0v = *reinterpret_cast<const float4*>(&Bs[k][tn * 8]);
            const float4 b1v = *reinterpret_cast<const float4*>(&Bs[k][tn * 8 + 4]);
            const float aa[8] = {a0v.x, a0v.y, a0v.z, a0v.w, a1v.x, a1v.y, a1v.z, a1v.w};
            const float bb[8] = {b0v.x, b0v.y, b0v.z, b0v.w, b1v.x, b1v.y, b1v.z, b1v.w};
#pragma unroll
            for (int i = 0; i < 8; ++i)
#pragma unroll
                for (int j = 0; j < 8; ++j)
                    acc[i][j] = fmaf(aa[i], bb[j], acc[i][j]);
        }
        __syncthreads();
    }
#pragma unroll
    for (int i = 0; i < 8; ++i) {
        const int o = m0 + tm * 8 + i;
        float* orow = outp + ((size_t)b * NCH + o) * NHW + n0 + tn * 8;
        float4 o0 = make_float4(acc[i][0], acc[i][1], acc[i][2], acc[i][3]);
        float4 o1 = make_float4(acc[i][4], acc[i][5], acc[i][6], acc[i][7]);
        if constexpr (MODE == 1) {
            const float bias = bp[o];
            const float* xr = xres + ((size_t)b * NCH + o) * NHW + n0 + tn * 8;
            const float4 x0 = *reinterpret_cast<const float4*>(xr);
            const float4 x1 = *reinterpret_cast<const float4*>(xr + 4);
            o0.x += bias + x0.x; o0.y += bias + x0.y; o0.z += bias + x0.z; o0.w += bias + x0.w;
            o1.x += bias + x1.x; o1.y += bias + x1.y; o1.z += bias + x1.z; o1.w += bias + x1.w;
        }
        *reinterpret_cast<float4*>(orow)     = o0;
        *reinterpret_cast<float4*>(orow + 4) = o1;
    }
}

// ============================================================
// Kernel 5: fused attention. One block per (b, head, 64-col tile of HW).
// LDS: qs[64c][64t] (scaled by 1/8), ks[64c][77s], vs[64c][77s],
//      ps[77s][64t] logits->probs, reduction scratch.
// ============================================================
__global__ __launch_bounds__(256) void k_attn(const float* __restrict__ q,
                                              const float* __restrict__ kv,
                                              float* __restrict__ hout) {
    __shared__ float sm[19392];
    float* qs     = sm;           // 4096  [c*64 + t]
    float* ks     = sm + 4096;    // 4928  [c*77 + s]
    float* vs     = sm + 9024;    // 4928  [c*77 + s]
    float* ps     = sm + 13952;   // 4928  [s*64 + t]
    float* redm   = sm + 18880;   // 256   [qq*64 + t]
    float* redsum = sm + 19136;   // 256
    const int t0  = blockIdx.x * 64;
    const int hh  = blockIdx.y;
    const int b   = blockIdx.z;
    const int tid = threadIdx.x;

    // ---- load Q tile (fold in scale^2 = 1/sqrt(hd) = 1/8) ----
    const float* qbase = q + ((size_t)b * NCH + hh * 64) * NHW + t0;
#pragma unroll
    for (int i = 0; i < 4; ++i) {
        const int f4 = i * 256 + tid;           // 0..1023 float4s
        const int c = f4 >> 4, t4 = (f4 & 15) * 4;
        float4 v = *reinterpret_cast<const float4*>(qbase + (size_t)c * NHW + t4);
        v.x *= 0.125f; v.y *= 0.125f; v.z *= 0.125f; v.w *= 0.125f;
        *reinterpret_cast<float4*>(&qs[c * 64 + t4]) = v;
    }
    // ---- load K/V (kv[b][s][hh*128 + j], j<64 -> K, else V) ----
    const float* kvb = kv + (size_t)b * NL * 1024 + hh * 128;
    for (int f = tid; f < NL * 128; f += 256) {
        const int s = f >> 7, j = f & 127;
        const float val = kvb[(size_t)s * 1024 + j];
        if (j < 64) ks[j * 77 + s] = val;
        else        vs[(j - 64) * 77 + s] = val;
    }
    __syncthreads();

    // ---- phase A: logits[t][s] = sum_c qs[c][t]*ks[c][s] ----
    {
        const int tb = tid & 15, sb = tid >> 4;
        const int s0 = sb * 5;                  // covers s in [0,80), mask >=77
        float lg[4][5];
#pragma unroll
        for (int i = 0; i < 4; ++i)
#pragma unroll
            for (int j = 0; j < 5; ++j) lg[i][j] = 0.f;
        for (int c = 0; c < 64; ++c) {
            const float4 qv = *reinterpret_cast<const float4*>(&qs[c * 64 + tb * 4]);
            float kk[5];
#pragma unroll
            for (int j = 0; j < 5; ++j) kk[j] = ks[c * 77 + s0 + j];  // tail reads spill into vs; masked below
#pragma unroll
            for (int j = 0; j < 5; ++j) {
                lg[0][j] = fmaf(qv.x, kk[j], lg[0][j]);
                lg[1][j] = fmaf(qv.y, kk[j], lg[1][j]);
                lg[2][j] = fmaf(qv.z, kk[j], lg[2][j]);
                lg[3][j] = fmaf(qv.w, kk[j], lg[3][j]);
            }
        }
#pragma unroll
        for (int j = 0; j < 5; ++j) {
            if (s0 + j < NL) {
#pragma unroll
                for (int i = 0; i < 4; ++i) ps[(s0 + j) * 64 + tb * 4 + i] = lg[i][j];
            }
        }
    }
    __syncthreads();

    // ---- phase B: softmax over s per t-column (4 threads/column) ----
    {
        const int t = tid & 63, qq = tid >> 6;
        float lmax = -1e30f;
        for (int s = qq; s < NL; s += 4) lmax = fmaxf(lmax, ps[s * 64 + t]);
        redm[qq * 64 + t] = lmax;
        __syncthreads();
        const float gmax = fmaxf(fmaxf(redm[t], redm[64 + t]), fmaxf(redm[128 + t], redm[192 + t]));
        float psum = 0.f;
        for (int s = qq; s < NL; s += 4) psum += __expf(ps[s * 64 + t] - gmax);
        redsum[qq * 64 + t] = psum;
        __syncthreads();
        const float inv = 1.f / (redsum[t] + redsum[64 + t] + redsum[128 + t] + redsum[192 + t]);
        for (int s = qq; s < NL; s += 4) ps[s * 64 + t] = __expf(ps[s * 64 + t] - gmax) * inv;
    }
    __syncthreads();

    // ---- phase C: h[c][t] = sum_s ps[s][t]*vs[c][s]; stage via qs ----
    {
        const int tb = tid & 15, cb = tid >> 4;
        float acc[4][4];
#pragma unroll
        for (int i = 0; i < 4; ++i)
#pragma unroll
            for (int j = 0; j < 4; ++j) acc[i][j] = 0.f;
        for (int s = 0; s < NL; ++s) {
            const float4 pv = *reinterpret_cast<const float4*>(&ps[s * 64 + tb * 4]);
#pragma unroll
            for (int j = 0; j < 4; ++j) {
                const float vv = vs[(cb * 4 + j) * 77 + s];
                acc[0][j] = fmaf(pv.x, vv, acc[0][j]);
                acc[1][j] = fmaf(pv.y, vv, acc[1][j]);
                acc[2][j] = fmaf(pv.z, vv, acc[2][j]);
                acc[3][j] = fmaf(pv.w, vv, acc[3][j]);
            }
        }
#pragma unroll
        for (int j = 0; j < 4; ++j) {
            *reinterpret_cast<float4*>(&qs[(cb * 4 + j) * 64 + tb * 4]) =
                make_float4(acc[0][j], acc[1][j], acc[2][j], acc[3][j]);
        }
    }
    __syncthreads();
    // ---- coalesced store ----
    float* hb = hout + ((size_t)b * NCH + hh * 64) * NHW + t0;
#pragma unroll
    for (int i = 0; i < 16; ++i) {
        const int f = i * 256 + tid;
        hb[(size_t)(f >> 6) * NHW + (f & 63)] = qs[f];
    }
}

// ============================================================
extern "C" void kernel_launch(void* const* d_in, const int* in_sizes, int n_in,
                              void* d_out, int out_size, void* d_ws, size_t ws_size,
                              hipStream_t stream) {
    const float* x   = (const float*)d_in[0];
    const float* t   = (const float*)d_in[1];
    const float* gnw = (const float*)d_in[2];
    const float* gnb = (const float*)d_in[3];
    const float* lnw = (const float*)d_in[4];
    const float* lnb = (const float*)d_in[5];
    const float* Wq  = (const float*)d_in[6];
    const float* Wkv = (const float*)d_in[7];
    const float* Wp  = (const float*)d_in[8];
    const float* bp  = (const float*)d_in[9];
    float* out = (float*)d_out;
    float* ws  = (float*)d_ws;

    // workspace layout (floats): needs ~85 MB
    float* mu  = ws;              // 1024
    float* rs  = ws + 1024;       // 1024
    float* tln = ws + 2048;       // 32*77*768  = 1,892,352
    float* kvb = ws + 1894400;    // 32*77*1024 = 2,523,136
    float* hbf = ws + 4417536;    // 32*512*1024 = 16,777,216
    float* qb  = out;             // q staged in d_out (overwritten by out-proj)

    k_gn_stats<<<dim3(NBATCH * 32), dim3(256), 0, stream>>>(x, mu, rs);
    k_ln<<<dim3(616), dim3(256), 0, stream>>>(t, lnw, lnb, tln);
    k_kv<<<dim3(8, 39), dim3(256), 0, stream>>>(tln, Wkv, kvb);
    k_proj<0><<<dim3(8, 4, NBATCH), dim3(256), 0, stream>>>(Wq, x, mu, rs, gnw, gnb,
                                                            nullptr, nullptr, qb);
    k_attn<<<dim3(16, NHEADS, NBATCH), dim3(256), 0, stream>>>(qb, kvb, hbf);
    k_proj<1><<<dim3(8, 4, NBATCH), dim3(256), 0, stream>>>(Wp, hbf, nullptr, nullptr,
                                                            nullptr, nullptr, bp, x, out);
}

// Round 7
// 507.775 us; speedup vs baseline: 1.4530x; 1.4530x over previous
//
#include <hip/hip_runtime.h>
#include <math.h>

#define NBATCH 32
#define NCH    512
#define NHW    1024
#define NL     77
#define ND     768
#define NHEADS 8

typedef __attribute__((ext_vector_type(8)))  short bf16x8;
typedef __attribute__((ext_vector_type(4)))  float f32x4;
typedef __attribute__((ext_vector_type(4)))  unsigned short ushort4v;
typedef __attribute__((ext_vector_type(8)))  unsigned short ushort8v;

typedef __attribute__((address_space(3))) unsigned int lds_u32;
typedef __attribute__((address_space(1))) const unsigned int glb_u32;

__device__ __forceinline__ void gl_lds16(const void* g, void* l) {
    __builtin_amdgcn_global_load_lds((glb_u32*)g, (lds_u32*)l, 16, 0, 0);
}

// split fp32 a ~= hi + lo, both RNE bf16
__device__ __forceinline__ void split2(float a, unsigned short& h, unsigned short& l) {
    unsigned u  = __float_as_uint(a);
    unsigned rh = (u + 0x7FFFu + ((u >> 16) & 1u)) & 0xFFFF0000u;
    h = (unsigned short)(rh >> 16);
    float res = a - __uint_as_float(rh);
    unsigned v  = __float_as_uint(res);
    unsigned rl = (v + 0x7FFFu + ((v >> 16) & 1u)) & 0xFFFF0000u;
    l = (unsigned short)(rl >> 16);
}

// ============================================================
// Kernel 1: GroupNorm statistics.
// ============================================================
__global__ __launch_bounds__(256) void k_gn_stats(const float* __restrict__ x,
                                                  float* __restrict__ mu_out,
                                                  float* __restrict__ rs_out) {
    const int bg = blockIdx.x;
    const float4* xv = reinterpret_cast<const float4*>(x) + (size_t)bg * 4096;
    float s = 0.f, q = 0.f;
#pragma unroll
    for (int i = 0; i < 16; ++i) {
        float4 v = xv[i * 256 + threadIdx.x];
        s += v.x + v.y + v.z + v.w;
        q += v.x * v.x + v.y * v.y + v.z * v.z + v.w * v.w;
    }
#pragma unroll
    for (int off = 32; off > 0; off >>= 1) {
        s += __shfl_down(s, off);
        q += __shfl_down(q, off);
    }
    __shared__ float rsh[8];
    const int wid = threadIdx.x >> 6;
    if ((threadIdx.x & 63) == 0) { rsh[wid] = s; rsh[4 + wid] = q; }
    __syncthreads();
    if (threadIdx.x == 0) {
        const float S  = rsh[0] + rsh[1] + rsh[2] + rsh[3];
        const float Q  = rsh[4] + rsh[5] + rsh[6] + rsh[7];
        const float mu = S * (1.f / 16384.f);
        const float var = Q * (1.f / 16384.f) - mu * mu;
        mu_out[bg] = mu;
        rs_out[bg] = 1.f / sqrtf(var + 1e-5f);
    }
}

// ============================================================
// Kernel 2: LayerNorm of t.
// ============================================================
__global__ __launch_bounds__(256) void k_ln(const float* __restrict__ t,
                                            const float* __restrict__ lw,
                                            const float* __restrict__ lb,
                                            float* __restrict__ tln) {
    const int row  = blockIdx.x * 4 + (threadIdx.x >> 6);
    const int lane = threadIdx.x & 63;
    const float4* tv = reinterpret_cast<const float4*>(t + (size_t)row * ND);
    float4 v[3];
    float s = 0.f, q = 0.f;
#pragma unroll
    for (int j = 0; j < 3; ++j) {
        v[j] = tv[lane + j * 64];
        s += v[j].x + v[j].y + v[j].z + v[j].w;
        q += v[j].x * v[j].x + v[j].y * v[j].y + v[j].z * v[j].z + v[j].w * v[j].w;
    }
#pragma unroll
    for (int off = 32; off > 0; off >>= 1) {
        s += __shfl_down(s, off);
        q += __shfl_down(q, off);
    }
    s = __shfl(s, 0);
    q = __shfl(q, 0);
    const float mu  = s * (1.f / 768.f);
    const float rsg = 1.f / sqrtf(q * (1.f / 768.f) - mu * mu + 1e-5f);
    float4* ov = reinterpret_cast<float4*>(tln + (size_t)row * ND);
    const float4* wv = reinterpret_cast<const float4*>(lw);
    const float4* bv = reinterpret_cast<const float4*>(lb);
#pragma unroll
    for (int j = 0; j < 3; ++j) {
        const float4 w = wv[lane + j * 64];
        const float4 bb = bv[lane + j * 64];
        float4 o;
        o.x = (v[j].x - mu) * rsg * w.x + bb.x;
        o.y = (v[j].y - mu) * rsg * w.y + bb.y;
        o.z = (v[j].z - mu) * rsg * w.z + bb.z;
        o.w = (v[j].w - mu) * rsg * w.w + bb.w;
        ov[lane + j * 64] = o;
    }
}

// ============================================================
// Kernel 3: KV projection GEMM (fp32).
// ============================================================
__global__ __launch_bounds__(256) void k_kv(const float* __restrict__ A,
                                            const float* __restrict__ Wkv,
                                            float* __restrict__ kvout) {
    __shared__ float As[16][68];
    __shared__ float Bs[16][132];
    const int n0 = blockIdx.x * 128;
    const int m0 = blockIdx.y * 64;
    const int tid = threadIdx.x;
    const int tm = tid & 15, tn = tid >> 4;
    float acc[4][8];
#pragma unroll
    for (int i = 0; i < 4; ++i)
#pragma unroll
        for (int j = 0; j < 8; ++j) acc[i][j] = 0.f;

    const int arow = tid >> 2, ak4 = (tid & 3) * 4;
    const int brow = tid >> 1, bk8 = (tid & 1) * 8;
    const int arow_g = min(m0 + arow, 2463);
    const float* Aptr = A + (size_t)arow_g * ND;
    const float* Bptr = Wkv + (size_t)(n0 + brow) * ND;

    for (int k0 = 0; k0 < ND; k0 += 16) {
        const float4 av = *reinterpret_cast<const float4*>(Aptr + k0 + ak4);
        const float4 b0 = *reinterpret_cast<const float4*>(Bptr + k0 + bk8);
        const float4 b1 = *reinterpret_cast<const float4*>(Bptr + k0 + bk8 + 4);
        As[ak4 + 0][arow] = av.x; As[ak4 + 1][arow] = av.y;
        As[ak4 + 2][arow] = av.z; As[ak4 + 3][arow] = av.w;
        Bs[bk8 + 0][brow] = b0.x; Bs[bk8 + 1][brow] = b0.y;
        Bs[bk8 + 2][brow] = b0.z; Bs[bk8 + 3][brow] = b0.w;
        Bs[bk8 + 4][brow] = b1.x; Bs[bk8 + 5][brow] = b1.y;
        Bs[bk8 + 6][brow] = b1.z; Bs[bk8 + 7][brow] = b1.w;
        __syncthreads();
#pragma unroll
        for (int k = 0; k < 16; ++k) {
            const float4 a  = *reinterpret_cast<const float4*>(&As[k][tm * 4]);
            const float4 p0 = *reinterpret_cast<const float4*>(&Bs[k][tn * 8]);
            const float4 p1 = *reinterpret_cast<const float4*>(&Bs[k][tn * 8 + 4]);
            const float aa[4] = {a.x, a.y, a.z, a.w};
            const float bb[8] = {p0.x, p0.y, p0.z, p0.w, p1.x, p1.y, p1.z, p1.w};
#pragma unroll
            for (int i = 0; i < 4; ++i)
#pragma unroll
                for (int j = 0; j < 8; ++j)
                    acc[i][j] = fmaf(aa[i], bb[j], acc[i][j]);
        }
        __syncthreads();
    }
#pragma unroll
    for (int i = 0; i < 4; ++i) {
        const int m = m0 + tm * 4 + i;
        if (m < 2464) {
            float* orow = kvout + (size_t)m * 1024 + n0 + tn * 8;
            *reinterpret_cast<float4*>(orow)     = make_float4(acc[i][0], acc[i][1], acc[i][2], acc[i][3]);
            *reinterpret_cast<float4*>(orow + 4) = make_float4(acc[i][4], acc[i][5], acc[i][6], acc[i][7]);
        }
    }
}

// ============================================================
// Kernel: split Wq and Wp into bf16 hi/lo.
// ============================================================
__global__ __launch_bounds__(256) void k_wsplit(const float* __restrict__ Wq, const float* __restrict__ Wp,
                                                unsigned short* __restrict__ qh, unsigned short* __restrict__ ql,
                                                unsigned short* __restrict__ ph, unsigned short* __restrict__ pl) {
    const int id = blockIdx.x * 256 + threadIdx.x;  // 0..131071
    const bool second = id >= 65536;
    const int e = (second ? id - 65536 : id) * 4;
    const float4 v = *reinterpret_cast<const float4*>((second ? Wp : Wq) + e);
    ushort4v h, l;
    split2(v.x, ((unsigned short*)&h)[0], ((unsigned short*)&l)[0]);
    split2(v.y, ((unsigned short*)&h)[1], ((unsigned short*)&l)[1]);
    split2(v.z, ((unsigned short*)&h)[2], ((unsigned short*)&l)[2]);
    split2(v.w, ((unsigned short*)&h)[3], ((unsigned short*)&l)[3]);
    *reinterpret_cast<ushort4v*>((second ? ph : qh) + e) = h;
    *reinterpret_cast<ushort4v*>((second ? pl : ql) + e) = l;
}

// ============================================================
// Kernel: GN-normalize x, transpose to [b][hw][c], split bf16 hi/lo.
// ============================================================
__global__ __launch_bounds__(256) void k_xsplit(const float* __restrict__ x,
                                                const float* __restrict__ mu,
                                                const float* __restrict__ rs,
                                                const float* __restrict__ gw,
                                                const float* __restrict__ gb,
                                                unsigned short* __restrict__ xhi,
                                                unsigned short* __restrict__ xlo) {
    __shared__ float tile[64][68];
    const int b = blockIdx.z, c0 = blockIdx.y * 64, hw0 = blockIdx.x * 64;
    const int tid = threadIdx.x;
    const int ci = tid >> 2, f4 = tid & 3;
    const int c = c0 + ci;
    const float sc = rs[b * 32 + (c >> 4)] * gw[c];
    const float sh = gb[c] - mu[b * 32 + (c >> 4)] * sc;
    const float* src = x + ((size_t)b * NCH + c) * NHW + hw0;
#pragma unroll
    for (int u = 0; u < 4; ++u) {
        float4 v = *reinterpret_cast<const float4*>(src + f4 * 16 + u * 4);
        v.x = v.x * sc + sh; v.y = v.y * sc + sh; v.z = v.z * sc + sh; v.w = v.w * sc + sh;
        *reinterpret_cast<float4*>(&tile[ci][f4 * 16 + u * 4]) = v;
    }
    __syncthreads();
    const int r = tid >> 2, cqi = tid & 3;  // r = hw row, cqi picks 16 channels
    union { ushort8v v[2]; unsigned short s[16]; } H, L;
#pragma unroll
    for (int j = 0; j < 16; ++j)
        split2(tile[cqi * 16 + j][r], H.s[j], L.s[j]);
    const size_t off = ((size_t)b * NHW + hw0 + r) * NCH + c0 + cqi * 16;
    *reinterpret_cast<ushort8v*>(xhi + off)     = H.v[0];
    *reinterpret_cast<ushort8v*>(xhi + off + 8) = H.v[1];
    *reinterpret_cast<ushort8v*>(xlo + off)     = L.v[0];
    *reinterpret_cast<ushort8v*>(xlo + off + 8) = L.v[1];
}

// ============================================================
// split-bf16 MFMA projection GEMM.
// out[b][o][n] = sum_c W[o][c] * X[b][n][c]   (X pre-transposed, bf16 hi/lo)
// = Whi*Xhi + Whi*Xlo + Wlo*Xhi  (3 MFMAs, ~fp32 accuracy)
// Block: 256(M) x 128(N), BK=32, 4 waves of 128x64, mfma_f32_16x16x32_bf16.
// LDS rows: 128B = 64B hi | 64B lo, XOR-swizzled by ((row&7)<<4);
// staged with global_load_lds(16B) using pre-swizzled per-lane sources.
// MODE 0: out = q (plain store). MODE 1: out = v + bp[o] + xres.
// ============================================================
template <int MODE>
__global__ __launch_bounds__(256, 2) void k_projm(const unsigned short* __restrict__ Whi,
                                                  const unsigned short* __restrict__ Wlo,
                                                  const unsigned short* __restrict__ Xhi,
                                                  const unsigned short* __restrict__ Xlo,
                                                  const float* __restrict__ bp,
                                                  const float* __restrict__ xres,
                                                  float* __restrict__ outp) {
    __shared__ char smem[49152];          // Ast 256x128B | Bst 128x128B
    const int tid  = threadIdx.x;
    const int lane = tid & 63;
    const int wv   = tid >> 6;            // wave 0..3
    const int wm   = wv >> 1, wn = wv & 1;
    const int n0 = blockIdx.x * 128;
    const int m0 = blockIdx.y * 256;
    const int b  = blockIdx.z;

    // staging lane role: dest byte = lane*16 within an 8-row x 128B chunk.
    // row-in-chunk = lane>>3, slot p = (lane&7)*16; unswizzled p' = p ^ ((row&7)<<4)
    // => p'/16 = (lane&7)^(lane>>3); p'>=64 selects lo buffer; c_off = 8*(x&3).
    const int xx   = (lane & 7) ^ (lane >> 3);
    const int coff = (xx & 3) * 8;
    const bool lof = xx >= 4;
    const unsigned short* aSrc = (lof ? Wlo : Whi) + (size_t)(m0 + wv * 64 + (lane >> 3)) * NCH + coff;
    const unsigned short* bSrc = (lof ? Xlo : Xhi) + ((size_t)b * NHW + n0 + wv * 32 + (lane >> 3)) * NCH + coff;
    char* aDst = smem + (wv * 64) * 128;
    char* bDst = smem + 32768 + (wv * 32) * 128;

    f32x4 acc[8][4];
#pragma unroll
    for (int i = 0; i < 8; ++i)
#pragma unroll
        for (int j = 0; j < 4; ++j) acc[i][j] = 0.f;

    const char* smA = smem;
    const char* smB = smem + 32768;
    const int swz   = (lane & 7) << 4;
    const int kcol  = (lane >> 4) << 4;   // k-group byte offset (0/16/32/48)
    const int rA0   = wm * 128 + (lane & 15);
    const int rB0   = wn * 64 + (lane & 15);

    for (int k0 = 0; k0 < NCH; k0 += 32) {
#pragma unroll
        for (int j = 0; j < 8; ++j)
            gl_lds16(aSrc + (size_t)j * 8 * NCH, aDst + j * 1024);
#pragma unroll
        for (int j = 0; j < 4; ++j)
            gl_lds16(bSrc + (size_t)j * 8 * NCH, bDst + j * 1024);
        __syncthreads();   // drains vmcnt(0) -> LDS tile ready

        bf16x8 bh[4], bl[4];
#pragma unroll
        for (int ni = 0; ni < 4; ++ni) {
            const int rb = (rB0 + ni * 16) * 128;
            bh[ni] = *reinterpret_cast<const bf16x8*>(smB + rb + (kcol ^ swz));
            bl[ni] = *reinterpret_cast<const bf16x8*>(smB + rb + ((64 + kcol) ^ swz));
        }
#pragma unroll
        for (int mi = 0; mi < 8; ++mi) {
            const int ra = (rA0 + mi * 16) * 128;
            const bf16x8 ah = *reinterpret_cast<const bf16x8*>(smA + ra + (kcol ^ swz));
            const bf16x8 al = *reinterpret_cast<const bf16x8*>(smA + ra + ((64 + kcol) ^ swz));
#pragma unroll
            for (int ni = 0; ni < 4; ++ni) {
                acc[mi][ni] = __builtin_amdgcn_mfma_f32_16x16x32_bf16(ah, bh[ni], acc[mi][ni], 0, 0, 0);
                acc[mi][ni] = __builtin_amdgcn_mfma_f32_16x16x32_bf16(ah, bl[ni], acc[mi][ni], 0, 0, 0);
                acc[mi][ni] = __builtin_amdgcn_mfma_f32_16x16x32_bf16(al, bh[ni], acc[mi][ni], 0, 0, 0);
            }
        }
        __syncthreads();   // before next stage overwrites
        aSrc += 32; bSrc += 32;
    }

    // epilogue: C/D layout col=lane&15, row=(lane>>4)*4+reg (m89-verified)
#pragma unroll
    for (int mi = 0; mi < 8; ++mi) {
#pragma unroll
        for (int ni = 0; ni < 4; ++ni) {
            const int colg = n0 + wn * 64 + ni * 16 + (lane & 15);
#pragma unroll
            for (int reg = 0; reg < 4; ++reg) {
                const int o = m0 + wm * 128 + mi * 16 + ((lane >> 4) << 2) + reg;
                float v = acc[mi][ni][reg];
                const size_t off = ((size_t)b * NCH + o) * NHW + colg;
                if constexpr (MODE == 1) v += bp[o] + xres[off];
                outp[off] = v;
            }
        }
    }
}

// ============================================================
// Kernel 5: fused attention (epilogue writes transposed bf16 hi/lo).
// ============================================================
__global__ __launch_bounds__(256) void k_attn(const float* __restrict__ q,
                                              const float* __restrict__ kv,
                                              unsigned short* __restrict__ hhi,
                                              unsigned short* __restrict__ hlo) {
    __shared__ float sm[19392];
    float* qs     = sm;           // 4096  [c*64 + t]
    float* ks     = sm + 4096;    // 4928  [c*77 + s]
    float* vs     = sm + 9024;    // 4928  [c*77 + s]
    float* ps     = sm + 13952;   // 4928  [s*64 + t]
    float* redm   = sm + 18880;
    float* redsum = sm + 19136;
    const int t0  = blockIdx.x * 64;
    const int hh  = blockIdx.y;
    const int b   = blockIdx.z;
    const int tid = threadIdx.x;

    const float* qbase = q + ((size_t)b * NCH + hh * 64) * NHW + t0;
#pragma unroll
    for (int i = 0; i < 4; ++i) {
        const int f4 = i * 256 + tid;
        const int c = f4 >> 4, t4 = (f4 & 15) * 4;
        float4 v = *reinterpret_cast<const float4*>(qbase + (size_t)c * NHW + t4);
        v.x *= 0.125f; v.y *= 0.125f; v.z *= 0.125f; v.w *= 0.125f;
        *reinterpret_cast<float4*>(&qs[c * 64 + t4]) = v;
    }
    const float* kvb = kv + (size_t)b * NL * 1024 + hh * 128;
    for (int f = tid; f < NL * 128; f += 256) {
        const int s = f >> 7, j = f & 127;
        const float val = kvb[(size_t)s * 1024 + j];
        if (j < 64) ks[j * 77 + s] = val;
        else        vs[(j - 64) * 77 + s] = val;
    }
    __syncthreads();

    {
        const int tb = tid & 15, sb = tid >> 4;
        const int s0 = sb * 5;
        float lg[4][5];
#pragma unroll
        for (int i = 0; i < 4; ++i)
#pragma unroll
            for (int j = 0; j < 5; ++j) lg[i][j] = 0.f;
        for (int c = 0; c < 64; ++c) {
            const float4 qv = *reinterpret_cast<const float4*>(&qs[c * 64 + tb * 4]);
            float kk[5];
#pragma unroll
            for (int j = 0; j < 5; ++j) kk[j] = ks[c * 77 + s0 + j];
#pragma unroll
            for (int j = 0; j < 5; ++j) {
                lg[0][j] = fmaf(qv.x, kk[j], lg[0][j]);
                lg[1][j] = fmaf(qv.y, kk[j], lg[1][j]);
                lg[2][j] = fmaf(qv.z, kk[j], lg[2][j]);
                lg[3][j] = fmaf(qv.w, kk[j], lg[3][j]);
            }
        }
#pragma unroll
        for (int j = 0; j < 5; ++j) {
            if (s0 + j < NL) {
#pragma unroll
                for (int i = 0; i < 4; ++i) ps[(s0 + j) * 64 + tb * 4 + i] = lg[i][j];
            }
        }
    }
    __syncthreads();

    {
        const int t = tid & 63, qq = tid >> 6;
        float lmax = -1e30f;
        for (int s = qq; s < NL; s += 4) lmax = fmaxf(lmax, ps[s * 64 + t]);
        redm[qq * 64 + t] = lmax;
        __syncthreads();
        const float gmax = fmaxf(fmaxf(redm[t], redm[64 + t]), fmaxf(redm[128 + t], redm[192 + t]));
        float psum = 0.f;
        for (int s = qq; s < NL; s += 4) psum += __expf(ps[s * 64 + t] - gmax);
        redsum[qq * 64 + t] = psum;
        __syncthreads();
        const float inv = 1.f / (redsum[t] + redsum[64 + t] + redsum[128 + t] + redsum[192 + t]);
        for (int s = qq; s < NL; s += 4) ps[s * 64 + t] = __expf(ps[s * 64 + t] - gmax) * inv;
    }
    __syncthreads();

    {
        const int tb = tid & 15, cb = tid >> 4;
        float acc[4][4];
#pragma unroll
        for (int i = 0; i < 4; ++i)
#pragma unroll
            for (int j = 0; j < 4; ++j) acc[i][j] = 0.f;
        for (int s = 0; s < NL; ++s) {
            const float4 pv = *reinterpret_cast<const float4*>(&ps[s * 64 + tb * 4]);
#pragma unroll
            for (int j = 0; j < 4; ++j) {
                const float vv = vs[(cb * 4 + j) * 77 + s];
                acc[0][j] = fmaf(pv.x, vv, acc[0][j]);
                acc[1][j] = fmaf(pv.y, vv, acc[1][j]);
                acc[2][j] = fmaf(pv.z, vv, acc[2][j]);
                acc[3][j] = fmaf(pv.w, vv, acc[3][j]);
            }
        }
#pragma unroll
        for (int j = 0; j < 4; ++j) {
            *reinterpret_cast<float4*>(&qs[(cb * 4 + j) * 64 + tb * 4]) =
                make_float4(acc[0][j], acc[1][j], acc[2][j], acc[3][j]);
        }
    }
    __syncthreads();
    // transposed bf16 hi/lo store: ht[b][t][c] for the out-projection
    {
        const int r = tid >> 2, cqi = tid & 3;    // r = t row (0..63), 16 channels each
        union { ushort8v v[2]; unsigned short s[16]; } H, L;
#pragma unroll
        for (int j = 0; j < 16; ++j)
            split2(qs[(cqi * 16 + j) * 64 + r], H.s[j], L.s[j]);
        const size_t off = ((size_t)b * NHW + t0 + r) * NCH + hh * 64 + cqi * 16;
        *reinterpret_cast<ushort8v*>(hhi + off)     = H.v[0];
        *reinterpret_cast<ushort8v*>(hhi + off + 8) = H.v[1];
        *reinterpret_cast<ushort8v*>(hlo + off)     = L.v[0];
        *reinterpret_cast<ushort8v*>(hlo + off + 8) = L.v[1];
    }
}

// ============================================================
extern "C" void kernel_launch(void* const* d_in, const int* in_sizes, int n_in,
                              void* d_out, int out_size, void* d_ws, size_t ws_size,
                              hipStream_t stream) {
    const float* x   = (const float*)d_in[0];
    const float* t   = (const float*)d_in[1];
    const float* gnw = (const float*)d_in[2];
    const float* gnb = (const float*)d_in[3];
    const float* lnw = (const float*)d_in[4];
    const float* lnb = (const float*)d_in[5];
    const float* Wq  = (const float*)d_in[6];
    const float* Wkv = (const float*)d_in[7];
    const float* Wp  = (const float*)d_in[8];
    const float* bp  = (const float*)d_in[9];
    float* out = (float*)d_out;
    float* ws  = (float*)d_ws;

    // workspace layout (floats), ~81 MiB total:
    float* mu  = ws;              // 1024
    float* rs  = ws + 1024;       // 1024
    float* tln = ws + 2048;       // 1,892,352 floats (dead after k_kv)
    float* kvb = ws + 1894400;    // 2,523,136 floats
    // W splits alias the (dead) tln region: 4 x 262144 ushorts = 512K floats
    unsigned short* wqh = (unsigned short*)(ws + 2048);
    unsigned short* wql = wqh + 262144;
    unsigned short* wph = wql + 262144;
    unsigned short* wpl = wph + 262144;
    // xt (GN'd, transposed, split) -> later reused as ht (attention output)
    unsigned short* xth = (unsigned short*)(ws + 4417536);   // 16,777,216 ushorts
    unsigned short* xtl = xth + 16777216;
    unsigned short* hth = xth;    // alias: xt dead after q-projection
    unsigned short* htl = xtl;
    float* qb = out;              // q staged in d_out (overwritten by out-proj)

    k_gn_stats<<<dim3(NBATCH * 32), dim3(256), 0, stream>>>(x, mu, rs);
    k_ln<<<dim3(616), dim3(256), 0, stream>>>(t, lnw, lnb, tln);
    k_kv<<<dim3(8, 39), dim3(256), 0, stream>>>(tln, Wkv, kvb);
    k_wsplit<<<dim3(512), dim3(256), 0, stream>>>(Wq, Wp, wqh, wql, wph, wpl);
    k_xsplit<<<dim3(16, 8, NBATCH), dim3(256), 0, stream>>>(x, mu, rs, gnw, gnb, xth, xtl);
    k_projm<0><<<dim3(8, 2, NBATCH), dim3(256), 0, stream>>>(wqh, wql, xth, xtl,
                                                             nullptr, nullptr, qb);
    k_attn<<<dim3(16, NHEADS, NBATCH), dim3(256), 0, stream>>>(qb, kvb, hth, htl);
    k_projm<1><<<dim3(8, 2, NBATCH), dim3(256), 0, stream>>>(wph, wpl, hth, htl,
                                                             bp, x, out);
}

// Round 10
// 456.052 us; speedup vs baseline: 1.6178x; 1.1134x over previous
//
#include <hip/hip_runtime.h>
#include <math.h>

#define NBATCH 32
#define NCH    512
#define NHW    1024
#define NL     77
#define ND     768
#define NHEADS 8

typedef __attribute__((ext_vector_type(8)))  short bf16x8;
typedef __attribute__((ext_vector_type(4)))  float f32x4;
typedef __attribute__((ext_vector_type(4)))  unsigned short ushort4v;
typedef __attribute__((ext_vector_type(8)))  unsigned short ushort8v;

typedef __attribute__((address_space(3))) unsigned int lds_u32;
typedef __attribute__((address_space(1))) const unsigned int glb_u32;

__device__ __forceinline__ void gl_lds16(const void* g, void* l) {
    __builtin_amdgcn_global_load_lds((glb_u32*)g, (lds_u32*)l, 16, 0, 0);
}

// split fp32 a ~= hi + lo, both RNE bf16
__device__ __forceinline__ void split2(float a, unsigned short& h, unsigned short& l) {
    unsigned u  = __float_as_uint(a);
    unsigned rh = (u + 0x7FFFu + ((u >> 16) & 1u)) & 0xFFFF0000u;
    h = (unsigned short)(rh >> 16);
    float res = a - __uint_as_float(rh);
    unsigned v  = __float_as_uint(res);
    unsigned rl = (v + 0x7FFFu + ((v >> 16) & 1u)) & 0xFFFF0000u;
    l = (unsigned short)(rl >> 16);
}

// ============================================================
// Kernel 1: GroupNorm statistics.
// ============================================================
__global__ __launch_bounds__(256) void k_gn_stats(const float* __restrict__ x,
                                                  float* __restrict__ mu_out,
                                                  float* __restrict__ rs_out) {
    const int bg = blockIdx.x;
    const float4* xv = reinterpret_cast<const float4*>(x) + (size_t)bg * 4096;
    float s = 0.f, q = 0.f;
#pragma unroll
    for (int i = 0; i < 16; ++i) {
        float4 v = xv[i * 256 + threadIdx.x];
        s += v.x + v.y + v.z + v.w;
        q += v.x * v.x + v.y * v.y + v.z * v.z + v.w * v.w;
    }
#pragma unroll
    for (int off = 32; off > 0; off >>= 1) {
        s += __shfl_down(s, off);
        q += __shfl_down(q, off);
    }
    __shared__ float rsh[8];
    const int wid = threadIdx.x >> 6;
    if ((threadIdx.x & 63) == 0) { rsh[wid] = s; rsh[4 + wid] = q; }
    __syncthreads();
    if (threadIdx.x == 0) {
        const float S  = rsh[0] + rsh[1] + rsh[2] + rsh[3];
        const float Q  = rsh[4] + rsh[5] + rsh[6] + rsh[7];
        const float mu = S * (1.f / 16384.f);
        const float var = Q * (1.f / 16384.f) - mu * mu;
        mu_out[bg] = mu;
        rs_out[bg] = 1.f / sqrtf(var + 1e-5f);
    }
}

// ============================================================
// Kernel 2: LayerNorm of t.
// ============================================================
__global__ __launch_bounds__(256) void k_ln(const float* __restrict__ t,
                                            const float* __restrict__ lw,
                                            const float* __restrict__ lb,
                                            float* __restrict__ tln) {
    const int row  = blockIdx.x * 4 + (threadIdx.x >> 6);
    const int lane = threadIdx.x & 63;
    const float4* tv = reinterpret_cast<const float4*>(t + (size_t)row * ND);
    float4 v[3];
    float s = 0.f, q = 0.f;
#pragma unroll
    for (int j = 0; j < 3; ++j) {
        v[j] = tv[lane + j * 64];
        s += v[j].x + v[j].y + v[j].z + v[j].w;
        q += v[j].x * v[j].x + v[j].y * v[j].y + v[j].z * v[j].z + v[j].w * v[j].w;
    }
#pragma unroll
    for (int off = 32; off > 0; off >>= 1) {
        s += __shfl_down(s, off);
        q += __shfl_down(q, off);
    }
    s = __shfl(s, 0);
    q = __shfl(q, 0);
    const float mu  = s * (1.f / 768.f);
    const float rsg = 1.f / sqrtf(q * (1.f / 768.f) - mu * mu + 1e-5f);
    float4* ov = reinterpret_cast<float4*>(tln + (size_t)row * ND);
    const float4* wv = reinterpret_cast<const float4*>(lw);
    const float4* bv = reinterpret_cast<const float4*>(lb);
#pragma unroll
    for (int j = 0; j < 3; ++j) {
        const float4 w = wv[lane + j * 64];
        const float4 bb = bv[lane + j * 64];
        float4 o;
        o.x = (v[j].x - mu) * rsg * w.x + bb.x;
        o.y = (v[j].y - mu) * rsg * w.y + bb.y;
        o.z = (v[j].z - mu) * rsg * w.z + bb.z;
        o.w = (v[j].w - mu) * rsg * w.w + bb.w;
        ov[lane + j * 64] = o;
    }
}

// ============================================================
// Kernel 3: KV projection GEMM (fp32).
// ============================================================
__global__ __launch_bounds__(256) void k_kv(const float* __restrict__ A,
                                            const float* __restrict__ Wkv,
                                            float* __restrict__ kvout) {
    __shared__ float As[16][68];
    __shared__ float Bs[16][132];
    const int n0 = blockIdx.x * 128;
    const int m0 = blockIdx.y * 64;
    const int tid = threadIdx.x;
    const int tm = tid & 15, tn = tid >> 4;
    float acc[4][8];
#pragma unroll
    for (int i = 0; i < 4; ++i)
#pragma unroll
        for (int j = 0; j < 8; ++j) acc[i][j] = 0.f;

    const int arow = tid >> 2, ak4 = (tid & 3) * 4;
    const int brow = tid >> 1, bk8 = (tid & 1) * 8;
    const int arow_g = min(m0 + arow, 2463);
    const float* Aptr = A + (size_t)arow_g * ND;
    const float* Bptr = Wkv + (size_t)(n0 + brow) * ND;

    for (int k0 = 0; k0 < ND; k0 += 16) {
        const float4 av = *reinterpret_cast<const float4*>(Aptr + k0 + ak4);
        const float4 b0 = *reinterpret_cast<const float4*>(Bptr + k0 + bk8);
        const float4 b1 = *reinterpret_cast<const float4*>(Bptr + k0 + bk8 + 4);
        As[ak4 + 0][arow] = av.x; As[ak4 + 1][arow] = av.y;
        As[ak4 + 2][arow] = av.z; As[ak4 + 3][arow] = av.w;
        Bs[bk8 + 0][brow] = b0.x; Bs[bk8 + 1][brow] = b0.y;
        Bs[bk8 + 2][brow] = b0.z; Bs[bk8 + 3][brow] = b0.w;
        Bs[bk8 + 4][brow] = b1.x; Bs[bk8 + 5][brow] = b1.y;
        Bs[bk8 + 6][brow] = b1.z; Bs[bk8 + 7][brow] = b1.w;
        __syncthreads();
#pragma unroll
        for (int k = 0; k < 16; ++k) {
            const float4 a  = *reinterpret_cast<const float4*>(&As[k][tm * 4]);
            const float4 p0 = *reinterpret_cast<const float4*>(&Bs[k][tn * 8]);
            const float4 p1 = *reinterpret_cast<const float4*>(&Bs[k][tn * 8 + 4]);
            const float aa[4] = {a.x, a.y, a.z, a.w};
            const float bb[8] = {p0.x, p0.y, p0.z, p0.w, p1.x, p1.y, p1.z, p1.w};
#pragma unroll
            for (int i = 0; i < 4; ++i)
#pragma unroll
                for (int j = 0; j < 8; ++j)
                    acc[i][j] = fmaf(aa[i], bb[j], acc[i][j]);
        }
        __syncthreads();
    }
#pragma unroll
    for (int i = 0; i < 4; ++i) {
        const int m = m0 + tm * 4 + i;
        if (m < 2464) {
            float* orow = kvout + (size_t)m * 1024 + n0 + tn * 8;
            *reinterpret_cast<float4*>(orow)     = make_float4(acc[i][0], acc[i][1], acc[i][2], acc[i][3]);
            *reinterpret_cast<float4*>(orow + 4) = make_float4(acc[i][4], acc[i][5], acc[i][6], acc[i][7]);
        }
    }
}

// ============================================================
// Kernel: split Wq and Wp into bf16 hi/lo.
// ============================================================
__global__ __launch_bounds__(256) void k_wsplit(const float* __restrict__ Wq, const float* __restrict__ Wp,
                                                unsigned short* __restrict__ qh, unsigned short* __restrict__ ql,
                                                unsigned short* __restrict__ ph, unsigned short* __restrict__ pl) {
    const int id = blockIdx.x * 256 + threadIdx.x;  // 0..131071
    const bool second = id >= 65536;
    const int e = (second ? id - 65536 : id) * 4;
    const float4 v = *reinterpret_cast<const float4*>((second ? Wp : Wq) + e);
    ushort4v h, l;
    split2(v.x, ((unsigned short*)&h)[0], ((unsigned short*)&l)[0]);
    split2(v.y, ((unsigned short*)&h)[1], ((unsigned short*)&l)[1]);
    split2(v.z, ((unsigned short*)&h)[2], ((unsigned short*)&l)[2]);
    split2(v.w, ((unsigned short*)&h)[3], ((unsigned short*)&l)[3]);
    *reinterpret_cast<ushort4v*>((second ? ph : qh) + e) = h;
    *reinterpret_cast<ushort4v*>((second ? pl : ql) + e) = l;
}

// ============================================================
// Kernel: GN-normalize x, transpose to [b][hw][c], split bf16 hi/lo.
// ============================================================
__global__ __launch_bounds__(256) void k_xsplit(const float* __restrict__ x,
                                                const float* __restrict__ mu,
                                                const float* __restrict__ rs,
                                                const float* __restrict__ gw,
                                                const float* __restrict__ gb,
                                                unsigned short* __restrict__ xhi,
                                                unsigned short* __restrict__ xlo) {
    __shared__ float tile[64][68];
    const int b = blockIdx.z, c0 = blockIdx.y * 64, hw0 = blockIdx.x * 64;
    const int tid = threadIdx.x;
    const int ci = tid >> 2, f4 = tid & 3;
    const int c = c0 + ci;
    const float sc = rs[b * 32 + (c >> 4)] * gw[c];
    const float sh = gb[c] - mu[b * 32 + (c >> 4)] * sc;
    const float* src = x + ((size_t)b * NCH + c) * NHW + hw0;
#pragma unroll
    for (int u = 0; u < 4; ++u) {
        float4 v = *reinterpret_cast<const float4*>(src + f4 * 16 + u * 4);
        v.x = v.x * sc + sh; v.y = v.y * sc + sh; v.z = v.z * sc + sh; v.w = v.w * sc + sh;
        *reinterpret_cast<float4*>(&tile[ci][f4 * 16 + u * 4]) = v;
    }
    __syncthreads();
    const int r = tid >> 2, cqi = tid & 3;  // r = hw row, cqi picks 16 channels
    union { ushort8v v[2]; unsigned short s[16]; } H, L;
#pragma unroll
    for (int j = 0; j < 16; ++j)
        split2(tile[cqi * 16 + j][r], H.s[j], L.s[j]);
    const size_t off = ((size_t)b * NHW + hw0 + r) * NCH + c0 + cqi * 16;
    *reinterpret_cast<ushort8v*>(xhi + off)     = H.v[0];
    *reinterpret_cast<ushort8v*>(xhi + off + 8) = H.v[1];
    *reinterpret_cast<ushort8v*>(xlo + off)     = L.v[0];
    *reinterpret_cast<ushort8v*>(xlo + off + 8) = L.v[1];
}

// ============================================================
// split-bf16 MFMA projection GEMM (validated round 7).
// ============================================================
template <int MODE>
__global__ __launch_bounds__(256, 2) void k_projm(const unsigned short* __restrict__ Whi,
                                                  const unsigned short* __restrict__ Wlo,
                                                  const unsigned short* __restrict__ Xhi,
                                                  const unsigned short* __restrict__ Xlo,
                                                  const float* __restrict__ bp,
                                                  const float* __restrict__ xres,
                                                  float* __restrict__ outp) {
    __shared__ char smem[49152];          // Ast 256x128B | Bst 128x128B
    const int tid  = threadIdx.x;
    const int lane = tid & 63;
    const int wv   = tid >> 6;            // wave 0..3
    const int wm   = wv >> 1, wn = wv & 1;
    const int n0 = blockIdx.x * 128;
    const int m0 = blockIdx.y * 256;
    const int b  = blockIdx.z;

    const int xx   = (lane & 7) ^ (lane >> 3);
    const int coff = (xx & 3) * 8;
    const bool lof = xx >= 4;
    const unsigned short* aSrc = (lof ? Wlo : Whi) + (size_t)(m0 + wv * 64 + (lane >> 3)) * NCH + coff;
    const unsigned short* bSrc = (lof ? Xlo : Xhi) + ((size_t)b * NHW + n0 + wv * 32 + (lane >> 3)) * NCH + coff;
    char* aDst = smem + (wv * 64) * 128;
    char* bDst = smem + 32768 + (wv * 32) * 128;

    f32x4 acc[8][4];
#pragma unroll
    for (int i = 0; i < 8; ++i)
#pragma unroll
        for (int j = 0; j < 4; ++j) acc[i][j] = 0.f;

    const char* smA = smem;
    const char* smB = smem + 32768;
    const int swz   = (lane & 7) << 4;
    const int kcol  = (lane >> 4) << 4;
    const int rA0   = wm * 128 + (lane & 15);
    const int rB0   = wn * 64 + (lane & 15);

    for (int k0 = 0; k0 < NCH; k0 += 32) {
#pragma unroll
        for (int j = 0; j < 8; ++j)
            gl_lds16(aSrc + (size_t)j * 8 * NCH, aDst + j * 1024);
#pragma unroll
        for (int j = 0; j < 4; ++j)
            gl_lds16(bSrc + (size_t)j * 8 * NCH, bDst + j * 1024);
        __syncthreads();

        bf16x8 bh[4], bl[4];
#pragma unroll
        for (int ni = 0; ni < 4; ++ni) {
            const int rb = (rB0 + ni * 16) * 128;
            bh[ni] = *reinterpret_cast<const bf16x8*>(smB + rb + (kcol ^ swz));
            bl[ni] = *reinterpret_cast<const bf16x8*>(smB + rb + ((64 + kcol) ^ swz));
        }
#pragma unroll
        for (int mi = 0; mi < 8; ++mi) {
            const int ra = (rA0 + mi * 16) * 128;
            const bf16x8 ah = *reinterpret_cast<const bf16x8*>(smA + ra + (kcol ^ swz));
            const bf16x8 al = *reinterpret_cast<const bf16x8*>(smA + ra + ((64 + kcol) ^ swz));
#pragma unroll
            for (int ni = 0; ni < 4; ++ni) {
                acc[mi][ni] = __builtin_amdgcn_mfma_f32_16x16x32_bf16(ah, bh[ni], acc[mi][ni], 0, 0, 0);
                acc[mi][ni] = __builtin_amdgcn_mfma_f32_16x16x32_bf16(ah, bl[ni], acc[mi][ni], 0, 0, 0);
                acc[mi][ni] = __builtin_amdgcn_mfma_f32_16x16x32_bf16(al, bh[ni], acc[mi][ni], 0, 0, 0);
            }
        }
        __syncthreads();
        aSrc += 32; bSrc += 32;
    }

#pragma unroll
    for (int mi = 0; mi < 8; ++mi) {
#pragma unroll
        for (int ni = 0; ni < 4; ++ni) {
            const int colg = n0 + wn * 64 + ni * 16 + (lane & 15);
#pragma unroll
            for (int reg = 0; reg < 4; ++reg) {
                const int o = m0 + wm * 128 + mi * 16 + ((lane >> 4) << 2) + reg;
                float v = acc[mi][ni][reg];
                const size_t off = ((size_t)b * NCH + o) * NHW + colg;
                if constexpr (MODE == 1) v += bp[o] + xres[off];
                outp[off] = v;
            }
        }
    }
}

// ============================================================
// Kernel 5: MFMA fused attention.
// Block = (b, head, 64-t tile); 4 waves x 16 t-rows.
// QK^T and PV via split-bf16 mfma_f32_16x16x32_bf16 (3 MFMAs each,
// ~fp32 accuracy); softmax fp32 in registers (no max-sub: logits
// ~N(0,1)); unnormalized P split hi/lo through LDS; 1/sum folded
// into the epilogue (inv stays in registers - same lane mapping).
// LDS 74.5 KiB: K [s][72c] hi/lo, V [c][104s] hi/lo,
// union{ Qstage fp32 [c][68t] | P [t][104s] hi/lo } across barrier B2.
// ============================================================
#define SP  104   // s-stride (ushorts) for vs, p
#define KSP 72    // c-stride (ushorts) for ks

__global__ __launch_bounds__(256) void k_attn(const float* __restrict__ q,
                                              const float* __restrict__ kv,
                                              unsigned short* __restrict__ hhi,
                                              unsigned short* __restrict__ hlo) {
    __shared__ char smem[76288];
    unsigned short* ks_hi = (unsigned short*)smem;               // [80][72]
    unsigned short* ks_lo = ks_hi + 80 * KSP;
    unsigned short* vs_hi = (unsigned short*)(smem + 23040);     // [64][104]
    unsigned short* vs_lo = vs_hi + 64 * SP;
    float*          qst   = (float*)(smem + 49664);              // [64][68] fp32
    unsigned short* p_hi  = (unsigned short*)(smem + 49664);     // [64][104]
    unsigned short* p_lo  = p_hi + 64 * SP;

    const int tid = threadIdx.x, lane = tid & 63, wv = tid >> 6;
    const int t0 = blockIdx.x * 64, hh = blockIdx.y, b = blockIdx.z;

    // ---- stage Q (x 1/8) into qst ----
    const float* qbase = q + ((size_t)b * NCH + hh * 64) * NHW + t0;
#pragma unroll
    for (int i = 0; i < 4; ++i) {
        const int f4 = i * 256 + tid;
        const int c = f4 >> 4, t4 = (f4 & 15) * 4;
        float4 v = *reinterpret_cast<const float4*>(qbase + (size_t)c * NHW + t4);
        v.x *= 0.125f; v.y *= 0.125f; v.z *= 0.125f; v.w *= 0.125f;
        *reinterpret_cast<float4*>(&qst[c * 68 + t4]) = v;
    }
    // ---- stage K/V, split to bf16 hi/lo ----
    const float* kvb = kv + (size_t)b * NL * 1024 + hh * 128;
#pragma unroll
    for (int i = 0; i < 10; ++i) {
        const int f4 = i * 256 + tid;           // 2464 float4s total
        if (f4 < NL * 32) {
            const int s = f4 >> 5, j4 = (f4 & 31) * 4;
            const float4 v = *reinterpret_cast<const float4*>(kvb + s * 1024 + j4);
            unsigned short h0, l0, h1, l1, h2, l2, h3, l3;
            split2(v.x, h0, l0); split2(v.y, h1, l1);
            split2(v.z, h2, l2); split2(v.w, h3, l3);
            if (j4 < 64) {
                ushort4v H = {h0, h1, h2, h3}, L = {l0, l1, l2, l3};
                *reinterpret_cast<ushort4v*>(&ks_hi[s * KSP + j4]) = H;
                *reinterpret_cast<ushort4v*>(&ks_lo[s * KSP + j4]) = L;
            } else {
                const int c = j4 - 64;
                vs_hi[(c + 0) * SP + s] = h0; vs_hi[(c + 1) * SP + s] = h1;
                vs_hi[(c + 2) * SP + s] = h2; vs_hi[(c + 3) * SP + s] = h3;
                vs_lo[(c + 0) * SP + s] = l0; vs_lo[(c + 1) * SP + s] = l1;
                vs_lo[(c + 2) * SP + s] = l2; vs_lo[(c + 3) * SP + s] = l3;
            }
        }
    }
    // zero pads: ks rows 77..79, vs cols 77..95
    for (int z = tid; z < 3 * KSP; z += 256) {
        const int r = 77 + z / KSP, cc = z % KSP;
        ks_hi[r * KSP + cc] = 0; ks_lo[r * KSP + cc] = 0;
    }
    for (int z = tid; z < 64 * 19; z += 256) {
        const int c = z / 19, s = 77 + z % 19;
        vs_hi[c * SP + s] = 0; vs_lo[c * SP + s] = 0;
    }
    __syncthreads();                                   // B1: tiles ready

    // ---- Q-fragments (transposed read + split), then free qst ----
    bf16x8 qfh[2], qfl[2];
    {
        const int tq = wv * 16 + (lane & 15);
#pragma unroll
        for (int ksx = 0; ksx < 2; ++ksx) {
            const int cbase = ksx * 32 + (lane >> 4) * 8;
            union { bf16x8 v; unsigned short u[8]; } H, L;
#pragma unroll
            for (int j = 0; j < 8; ++j)
                split2(qst[(cbase + j) * 68 + tq], H.u[j], L.u[j]);
            qfh[ksx] = H.v; qfl[ksx] = L.v;
        }
    }
    __syncthreads();                                   // B2: qst dead, P writable

    // zero P pad s in [80,96)
    for (int z = tid; z < 64 * 16; z += 256) {
        const int t = z >> 4, s = 80 + (z & 15);
        p_hi[t * SP + s] = 0; p_lo[t * SP + s] = 0;
    }

    // ---- QK^T: logits[t][s], t = wave's 16 rows, s in [0,80) ----
    f32x4 acc[5];
#pragma unroll
    for (int sn = 0; sn < 5; ++sn) acc[sn] = 0.f;
#pragma unroll
    for (int sn = 0; sn < 5; ++sn) {
        const int row = sn * 16 + (lane & 15);
#pragma unroll
        for (int ksx = 0; ksx < 2; ++ksx) {
            const int co = ksx * 32 + (lane >> 4) * 8;
            const bf16x8 kh = *reinterpret_cast<const bf16x8*>(&ks_hi[row * KSP + co]);
            const bf16x8 kl = *reinterpret_cast<const bf16x8*>(&ks_lo[row * KSP + co]);
            acc[sn] = __builtin_amdgcn_mfma_f32_16x16x32_bf16(qfh[ksx], kh, acc[sn], 0, 0, 0);
            acc[sn] = __builtin_amdgcn_mfma_f32_16x16x32_bf16(qfh[ksx], kl, acc[sn], 0, 0, 0);
            acc[sn] = __builtin_amdgcn_mfma_f32_16x16x32_bf16(qfl[ksx], kh, acc[sn], 0, 0, 0);
        }
    }

    // ---- softmax (unnormalized, fp32, in registers) ----
    const int sl = lane & 15;
    float pe[5][4];
    float rowsum[4] = {0.f, 0.f, 0.f, 0.f};
#pragma unroll
    for (int sn = 0; sn < 5; ++sn) {
        const int s = sn * 16 + sl;
#pragma unroll
        for (int r = 0; r < 4; ++r) {
            float p = __expf(acc[sn][r]);
            p = (s < NL) ? p : 0.f;
            pe[sn][r] = p;
            rowsum[r] += p;
        }
    }
#pragma unroll
    for (int r = 0; r < 4; ++r) {
#pragma unroll
        for (int m = 1; m < 16; m <<= 1)
            rowsum[r] += __shfl_xor(rowsum[r], m);
    }
    float inv[4];
#pragma unroll
    for (int r = 0; r < 4; ++r) inv[r] = 1.f / rowsum[r];

    // P -> LDS (hi/lo), layout [t_local][s]
#pragma unroll
    for (int sn = 0; sn < 5; ++sn) {
        const int s = sn * 16 + sl;
#pragma unroll
        for (int r = 0; r < 4; ++r) {
            const int t = wv * 16 + (lane >> 4) * 4 + r;
            unsigned short ph, pl;
            split2(pe[sn][r], ph, pl);
            p_hi[t * SP + s] = ph;
            p_lo[t * SP + s] = pl;
        }
    }
    __syncthreads();                                   // B3: P ready

    // ---- PV: h[t][c] = sum_s P[t][s] * v[c][s] ----
    f32x4 hacc[4];
#pragma unroll
    for (int nt = 0; nt < 4; ++nt) hacc[nt] = 0.f;
#pragma unroll
    for (int ksx = 0; ksx < 3; ++ksx) {
        const int trow = wv * 16 + (lane & 15);
        const int so = ksx * 32 + (lane >> 4) * 8;
        const bf16x8 pah = *reinterpret_cast<const bf16x8*>(&p_hi[trow * SP + so]);
        const bf16x8 pal = *reinterpret_cast<const bf16x8*>(&p_lo[trow * SP + so]);
#pragma unroll
        for (int nt = 0; nt < 4; ++nt) {
            const int crow = nt * 16 + (lane & 15);
            const bf16x8 vh = *reinterpret_cast<const bf16x8*>(&vs_hi[crow * SP + so]);
            const bf16x8 vl = *reinterpret_cast<const bf16x8*>(&vs_lo[crow * SP + so]);
            hacc[nt] = __builtin_amdgcn_mfma_f32_16x16x32_bf16(pah, vh, hacc[nt], 0, 0, 0);
            hacc[nt] = __builtin_amdgcn_mfma_f32_16x16x32_bf16(pah, vl, hacc[nt], 0, 0, 0);
            hacc[nt] = __builtin_amdgcn_mfma_f32_16x16x32_bf16(pal, vh, hacc[nt], 0, 0, 0);
        }
    }

    // ---- epilogue: h * inv -> split bf16 -> ht[b][t][c] ----
#pragma unroll
    for (int nt = 0; nt < 4; ++nt) {
        const int cg = hh * 64 + nt * 16 + (lane & 15);
#pragma unroll
        for (int r = 0; r < 4; ++r) {
            const int t = t0 + wv * 16 + (lane >> 4) * 4 + r;
            const float hvf = hacc[nt][r] * inv[r];
            unsigned short hb, lb;
            split2(hvf, hb, lb);
            const size_t off = ((size_t)b * NHW + t) * NCH + cg;
            hhi[off] = hb;
            hlo[off] = lb;
        }
    }
}

// ============================================================
extern "C" void kernel_launch(void* const* d_in, const int* in_sizes, int n_in,
                              void* d_out, int out_size, void* d_ws, size_t ws_size,
                              hipStream_t stream) {
    const float* x   = (const float*)d_in[0];
    const float* t   = (const float*)d_in[1];
    const float* gnw = (const float*)d_in[2];
    const float* gnb = (const float*)d_in[3];
    const float* lnw = (const float*)d_in[4];
    const float* lnb = (const float*)d_in[5];
    const float* Wq  = (const float*)d_in[6];
    const float* Wkv = (const float*)d_in[7];
    const float* Wp  = (const float*)d_in[8];
    const float* bp  = (const float*)d_in[9];
    float* out = (float*)d_out;
    float* ws  = (float*)d_ws;

    // workspace layout (floats), ~81 MiB total:
    float* mu  = ws;              // 1024
    float* rs  = ws + 1024;       // 1024
    float* tln = ws + 2048;       // 1,892,352 floats (dead after k_kv)
    float* kvb = ws + 1894400;    // 2,523,136 floats
    unsigned short* wqh = (unsigned short*)(ws + 2048);   // aliases dead tln
    unsigned short* wql = wqh + 262144;
    unsigned short* wph = wql + 262144;
    unsigned short* wpl = wph + 262144;
    unsigned short* xth = (unsigned short*)(ws + 4417536);   // 16,777,216 ushorts
    unsigned short* xtl = xth + 16777216;
    unsigned short* hth = xth;    // alias: xt dead after q-projection
    unsigned short* htl = xtl;
    float* qb = out;              // q staged in d_out (overwritten by out-proj)

    k_gn_stats<<<dim3(NBATCH * 32), dim3(256), 0, stream>>>(x, mu, rs);
    k_ln<<<dim3(616), dim3(256), 0, stream>>>(t, lnw, lnb, tln);
    k_kv<<<dim3(8, 39), dim3(256), 0, stream>>>(tln, Wkv, kvb);
    k_wsplit<<<dim3(512), dim3(256), 0, stream>>>(Wq, Wp, wqh, wql, wph, wpl);
    k_xsplit<<<dim3(16, 8, NBATCH), dim3(256), 0, stream>>>(x, mu, rs, gnw, gnb, xth, xtl);
    k_projm<0><<<dim3(8, 2, NBATCH), dim3(256), 0, stream>>>(wqh, wql, xth, xtl,
                                                             nullptr, nullptr, qb);
    k_attn<<<dim3(16, NHEADS, NBATCH), dim3(256), 0, stream>>>(qb, kvb, hth, htl);
    k_projm<1><<<dim3(8, 2, NBATCH), dim3(256), 0, stream>>>(wph, wpl, hth, htl,
                                                             bp, x, out);
}